// Round 4
// baseline (483.054 us; speedup 1.0000x reference)
//
#include <hip/hip_runtime.h>

typedef unsigned short ushortT;
typedef __attribute__((ext_vector_type(8))) short short8;
typedef __attribute__((ext_vector_type(4))) float f32x4;

#define QSCALE 0.18033688011112042f  // (1/sqrt(64)) * log2(e)

__device__ __forceinline__ ushortT f2bf(float f) {
  union { float f; unsigned int u; } v; v.f = f;
  unsigned int r = v.u + 0x7FFFu + ((v.u >> 16) & 1u);
  return (ushortT)(r >> 16);
}

// pack two f32 -> bf16x2 (round-half-up), low16 = a, high16 = b
__device__ __forceinline__ unsigned int pk2bf(float a, float b) {
  union { float f; unsigned int u; } ua, ub; ua.f = a; ub.f = b;
  return __builtin_amdgcn_perm(ub.u + 0x8000u, ua.u + 0x8000u, 0x07060302u);
}

// gfx950 cross-quadrow swap pair: after both swaps,
// a = [A0,A2,B0,B2], b = [A1,A3,B1,B3] (16-lane chunks)
__device__ __forceinline__ void pl_swap(unsigned int& a, unsigned int& b) {
  asm("v_permlane32_swap_b32 %0, %1" : "+v"(a), "+v"(b));
  asm("v_permlane16_swap_b32 %0, %1" : "+v"(a), "+v"(b));
}

__device__ __forceinline__ void gld_lds16(const void* g, void* l) {
  __builtin_amdgcn_global_load_lds(
      (const __attribute__((address_space(1))) unsigned int*)g,
      (__attribute__((address_space(3))) unsigned int*)l, 16, 0, 0);
}

// ---------------- fp32 -> bf16 convert ----------------
__global__ __launch_bounds__(256) void cvt_kernel(const float* __restrict__ src,
                                                  ushortT* __restrict__ dst, int n4) {
  int i = blockIdx.x * 256 + threadIdx.x;
  if (i < n4) {
    float4 v = ((const float4*)src)[i];
    ushort4 o;
    o.x = f2bf(v.x); o.y = f2bf(v.y); o.z = f2bf(v.z); o.w = f2bf(v.w);
    ((ushort4*)dst)[i] = o;
  }
}

// ---------------- LayerNorm: fp32 in, bf16 out ----------------
__global__ __launch_bounds__(256) void ln_kernel(const float* __restrict__ x,
                                                 const float* __restrict__ g,
                                                 const float* __restrict__ be,
                                                 ushortT* __restrict__ xn) {
  const int row = blockIdx.x, tid = threadIdx.x;
  const float4 v = ((const float4*)(x + (size_t)row * 1024))[tid];
  float s1 = v.x + v.y + v.z + v.w;
  float s2 = v.x * v.x + v.y * v.y + v.z * v.z + v.w * v.w;
#pragma unroll
  for (int off = 32; off >= 1; off >>= 1) {
    s1 += __shfl_xor(s1, off, 64);
    s2 += __shfl_xor(s2, off, 64);
  }
  __shared__ float red[8];
  const int wave = tid >> 6, lane = tid & 63;
  if (lane == 0) { red[wave] = s1; red[4 + wave] = s2; }
  __syncthreads();
  s1 = red[0] + red[1] + red[2] + red[3];
  s2 = red[4] + red[5] + red[6] + red[7];
  const float mean = s1 * (1.0f / 1024.0f);
  const float var  = s2 * (1.0f / 1024.0f) - mean * mean;
  const float rs = rsqrtf(var + 1e-5f);
  const float4 gv = ((const float4*)g)[tid];
  const float4 bv = ((const float4*)be)[tid];
  ushort4 o;
  o.x = f2bf((v.x - mean) * rs * gv.x + bv.x);
  o.y = f2bf((v.y - mean) * rs * gv.y + bv.y);
  o.z = f2bf((v.z - mean) * rs * gv.z + bv.z);
  o.w = f2bf((v.w - mean) * rs * gv.w + bv.w);
  ((ushort4*)xn)[(size_t)row * 256 + tid] = o;
}

// ---------------- GEMM C[M,N] = A[M,K] * B[N,K]^T (both bf16, K-major) ----
// MODE 0: fp32 out + bias (final projection).  MODE 1: QKV scatter epilogue.
template <int MODE>
__global__ __launch_bounds__(256, 2) void gemm_bt(
    const ushortT* __restrict__ A, const ushortT* __restrict__ Bm,
    int M, int N, int K,
    ushortT* __restrict__ qbuf, ushortT* __restrict__ kbuf, ushortT* __restrict__ vbuf,
    float* __restrict__ outf, const float* __restrict__ bias) {
  __shared__ ushortT lds_a[128 * 64];
  __shared__ ushortT lds_b[128 * 64];
  const int tid = threadIdx.x;
  const int wave = tid >> 6, lane = tid & 63;
  const int q4 = lane >> 4, l16 = lane & 15;
  const int m0 = blockIdx.y * 128, n0 = blockIdx.x * 128;
  const int wm = (wave >> 1) * 64, wn = (wave & 1) * 64;
  const int srow = lane >> 3, scol = (lane & 7) * 8;  // staging: 8 rows x 64 cols / inst

  f32x4 acc[4][4];
#pragma unroll
  for (int i = 0; i < 4; i++)
#pragma unroll
    for (int j = 0; j < 4; j++) acc[i][j] = (f32x4){0.f, 0.f, 0.f, 0.f};

  for (int k0 = 0; k0 < K; k0 += 64) {
#pragma unroll
    for (int j = 0; j < 4; j++) {
      const int q = wave * 4 + j;  // chunk 0..15, 8 rows each
      gld_lds16(&A[(size_t)(m0 + q * 8 + srow) * K + (k0 + scol)], &lds_a[q * 512]);
      gld_lds16(&Bm[(size_t)(n0 + q * 8 + srow) * K + (k0 + scol)], &lds_b[q * 512]);
    }
    __syncthreads();  // drains vmcnt -> staged data visible
#pragma unroll
    for (int kk = 0; kk < 2; kk++) {
      short8 af[4], bf[4];
#pragma unroll
      for (int i = 0; i < 4; i++)
        af[i] = *(const short8*)&lds_a[(wm + i * 16 + l16) * 64 + kk * 32 + q4 * 8];
#pragma unroll
      for (int i = 0; i < 4; i++)
        bf[i] = *(const short8*)&lds_b[(wn + i * 16 + l16) * 64 + kk * 32 + q4 * 8];
#pragma unroll
      for (int im = 0; im < 4; im++)
#pragma unroll
        for (int in = 0; in < 4; in++)
          acc[im][in] = __builtin_amdgcn_mfma_f32_16x16x32_bf16(af[im], bf[in], acc[im][in], 0, 0, 0);
    }
    __syncthreads();  // all waves done reading before next stage overwrites
  }

  // Epilogue. C/D layout: col = lane&15, row = (lane>>4)*4 + reg.
#pragma unroll
  for (int im = 0; im < 4; im++) {
    const int grow_base = m0 + wm + im * 16 + q4 * 4;
#pragma unroll
    for (int in = 0; in < 4; in++) {
      const int c = n0 + wn + in * 16 + l16;
#pragma unroll
      for (int r = 0; r < 4; r++) {
        const float v = acc[im][in][r];
        const int grow = grow_base + r;
        if (MODE == 0) {
          outf[(size_t)grow * N + c] = v + bias[c];
        } else {
          const int which = c >> 10;          // 0=q 1=k 2=v (uniform per 16-tile)
          const int h = (c >> 6) & 15;
          const int d = c & 63;
          const int b = grow >> 11, n = grow & 2047;
          if (which == 0) {
            qbuf[((size_t)(b * 16 + h) * 2048 + n) * 64 + d] = f2bf(v * QSCALE);
          } else if (which == 1) {
            kbuf[((size_t)(b * 16 + h) * 2048 + n) * 64 + d] = f2bf(v);
          } else {  // V stored transposed: [B,H,dh,N]
            vbuf[((size_t)(b * 16 + h) * 64 + d) * 2048 + n] = f2bf(v);
          }
        }
      }
    }
  }
}

// ---------------- Flash attention, S^T formulation, max-free softmax -------
// Q [B,H,N,64] (pre-scaled into log2 domain), K [B,H,N,64], Vt [B,H,64,N].
// Max-free: log2-domain scores are O(10) << 127, softmax shift-invariant,
// so P = exp2(s), l = sum. No LDS at all: P C-layout -> B-operand layout via
// gfx950 v_permlane{16,32}_swap_b32 (in-register quad-row transpose).
// Explicit K prefetch (next tile) + early V issue hide global latency.
// 1 wave = 32 queries; block = 2 waves = 64 queries (waves independent).
__global__ __launch_bounds__(128) void attn_kernel(
    const ushortT* __restrict__ Qb, const ushortT* __restrict__ Kb,
    const ushortT* __restrict__ Vt, ushortT* __restrict__ Ob) {
  const int tid = threadIdx.x;
  const int wave = tid >> 6, lane = tid & 63;
  const int q4 = lane >> 4, l16 = lane & 15;
  const int blk = blockIdx.x;
  const int bh = blk & 63, qt = blk >> 6;  // same-bh blocks 64 apart -> same XCD
  const ushortT* Qp = Qb + (size_t)bh * (2048 * 64);
  const ushortT* Kp = Kb + (size_t)bh * (2048 * 64);
  const ushortT* Vp = Vt + (size_t)bh * (64 * 2048);
  const int qrow0 = qt * 64 + wave * 32;

  // Q fragments (B-operand: n=q=l16, k=dim=q4*8+j), qn in {0,1}, kk dim-chunk
  short8 qf[2][2];
#pragma unroll
  for (int qn = 0; qn < 2; qn++)
#pragma unroll
    for (int kk = 0; kk < 2; kk++)
      qf[qn][kk] = *(const short8*)&Qp[(size_t)(qrow0 + qn * 16 + l16) * 64 + kk * 32 + q4 * 8];

  f32x4 acc[4][2];  // O^T accum [dn][qn], C-layout: d=dn*16+q4*4+r, q=l16
#pragma unroll
  for (int dn = 0; dn < 4; dn++)
#pragma unroll
    for (int qn = 0; qn < 2; qn++) acc[dn][qn] = (f32x4){0.f, 0.f, 0.f, 0.f};
  float lsum[2] = {0.f, 0.f};  // per-lane partial softmax denominator

  // preload K fragments for the first tile (A-operand: m=key=l16, k=q4*8+j)
  short8 kf[4][2];
#pragma unroll
  for (int cn = 0; cn < 4; cn++)
#pragma unroll
    for (int kk = 0; kk < 2; kk++)
      kf[cn][kk] = *(const short8*)&Kp[(size_t)(cn * 16 + l16) * 64 + kk * 32 + q4 * 8];

  for (int s0 = 0; s0 < 2048; s0 += 64) {
    // ---- issue V loads now; consumed only after softmax (~300 cy slack)
    short8 vf[4][2];
#pragma unroll
    for (int dn = 0; dn < 4; dn++)
#pragma unroll
      for (int kk = 0; kk < 2; kk++)
        vf[dn][kk] = *(const short8*)&Vp[(size_t)(dn * 16 + l16) * 2048 + s0 + kk * 32 + q4 * 8];

    // ---- S^T = K·Q^T : sa[qn][cn][r] = S^T[key=cn*16+q4*4+r][q=qn*16+l16]
    f32x4 sa[2][4];
#pragma unroll
    for (int qn = 0; qn < 2; qn++)
#pragma unroll
      for (int cn = 0; cn < 4; cn++) sa[qn][cn] = (f32x4){0.f, 0.f, 0.f, 0.f};
#pragma unroll
    for (int cn = 0; cn < 4; cn++)
#pragma unroll
      for (int qn = 0; qn < 2; qn++) {
        sa[qn][cn] = __builtin_amdgcn_mfma_f32_16x16x32_bf16(kf[cn][0], qf[qn][0], sa[qn][cn], 0, 0, 0);
        sa[qn][cn] = __builtin_amdgcn_mfma_f32_16x16x32_bf16(kf[cn][1], qf[qn][1], sa[qn][cn], 0, 0, 0);
      }

    // ---- prefetch next tile's K (kf regs just freed by the MFMAs above)
    const int sn = (s0 + 64) & 2047;  // wrap: harmless valid-memory load on last iter
#pragma unroll
    for (int cn = 0; cn < 4; cn++)
#pragma unroll
      for (int kk = 0; kk < 2; kk++)
        kf[cn][kk] = *(const short8*)&Kp[(size_t)(sn + cn * 16 + l16) * 64 + kk * 32 + q4 * 8];

    // ---- max-free softmax: P = exp2(s); per-lane denominator; pack pairs
    unsigned int w[2][4][2];
#pragma unroll
    for (int qn = 0; qn < 2; qn++)
#pragma unroll
      for (int cn = 0; cn < 4; cn++) {
        float p0 = __builtin_amdgcn_exp2f(sa[qn][cn][0]);
        float p1 = __builtin_amdgcn_exp2f(sa[qn][cn][1]);
        float p2 = __builtin_amdgcn_exp2f(sa[qn][cn][2]);
        float p3 = __builtin_amdgcn_exp2f(sa[qn][cn][3]);
        lsum[qn] += (p0 + p1) + (p2 + p3);
        w[qn][cn][0] = pk2bf(p0, p1);
        w[qn][cn][1] = pk2bf(p2, p3);
      }

    // ---- in-register transpose: C-layout pairs -> B-operand fragments.
    // pf[qn][ks] reg p (lane q4,l16) = w[qn][2ks+(q4>>1)][p&1]
    //   pulled from lane ((q4&1)*2+(p>>1), l16)  == permlane32+16 swap pair.
    short8 pf[2][2];
#pragma unroll
    for (int qn = 0; qn < 2; qn++)
#pragma unroll
      for (int ks = 0; ks < 2; ks++) {
        unsigned int a0 = w[qn][2 * ks][0], b0 = w[qn][2 * ks + 1][0];
        unsigned int a1 = w[qn][2 * ks][1], b1 = w[qn][2 * ks + 1][1];
        pl_swap(a0, b0);
        pl_swap(a1, b1);
        union { unsigned int u[4]; short8 s; } t;
        t.u[0] = a0; t.u[1] = a1; t.u[2] = b0; t.u[3] = b1;
        pf[qn][ks] = t.s;
      }

    // ---- O^T += V^T·P^T
#pragma unroll
    for (int dn = 0; dn < 4; dn++)
#pragma unroll
      for (int qn = 0; qn < 2; qn++) {
        acc[dn][qn] = __builtin_amdgcn_mfma_f32_16x16x32_bf16(vf[dn][0], pf[qn][0], acc[dn][qn], 0, 0, 0);
        acc[dn][qn] = __builtin_amdgcn_mfma_f32_16x16x32_bf16(vf[dn][1], pf[qn][1], acc[dn][qn], 0, 0, 0);
      }
  }

  // ---- epilogue: reduce denominator across the 4 q4 groups, write O^T
  const int b = bh >> 4, h = bh & 15;
#pragma unroll
  for (int qn = 0; qn < 2; qn++) {
    float l = lsum[qn];
    l += __shfl_xor(l, 16, 64);
    l += __shfl_xor(l, 32, 64);
    const float inv = 1.0f / l;
    const size_t row = (size_t)(b * 2048 + qrow0 + qn * 16 + l16) * 1024 + h * 64;
#pragma unroll
    for (int dn = 0; dn < 4; dn++) {
      ushort4 o;
      o.x = f2bf(acc[dn][qn][0] * inv);
      o.y = f2bf(acc[dn][qn][1] * inv);
      o.z = f2bf(acc[dn][qn][2] * inv);
      o.w = f2bf(acc[dn][qn][3] * inv);
      *(ushort4*)&Ob[row + dn * 16 + q4 * 4] = o;
    }
  }
}

extern "C" void kernel_launch(void* const* d_in, const int* in_sizes, int n_in,
                              void* d_out, int out_size, void* d_ws, size_t ws_size,
                              hipStream_t stream) {
  const float* x    = (const float*)d_in[0];
  const float* g    = (const float*)d_in[1];
  const float* be   = (const float*)d_in[2];
  const float* wqkv = (const float*)d_in[3];
  const float* wout = (const float*)d_in[4];
  const float* bout = (const float*)d_in[5];
  float* out = (float*)d_out;

  char* ws = (char*)d_ws;
  ushortT* xn = (ushortT*)(ws + 0);                    // 16 MB  [8192,1024] bf16
  ushortT* wq = (ushortT*)(ws + 16777216);             //  6 MB  [3072,1024] bf16
  ushortT* wo = (ushortT*)(ws + 23068672);             //  2 MB  [1024,1024] bf16
  ushortT* Qb = (ushortT*)(ws + 25165824);             // 16 MB  [B,H,N,64]
  ushortT* Kb = (ushortT*)(ws + 41943040);             // 16 MB  [B,H,N,64]
  ushortT* Vt = (ushortT*)(ws + 58720256);             // 16 MB  [B,H,64,N]
  ushortT* Ob = (ushortT*)(ws + 75497472);             // 16 MB  [8192,1024]

  cvt_kernel<<<3072, 256, 0, stream>>>(wqkv, wq, 786432);
  cvt_kernel<<<1024, 256, 0, stream>>>(wout, wo, 262144);
  ln_kernel<<<8192, 256, 0, stream>>>(x, g, be, xn);
  gemm_bt<1><<<dim3(24, 64), 256, 0, stream>>>(xn, wq, 8192, 3072, 1024,
                                               Qb, Kb, Vt, nullptr, nullptr);
  attn_kernel<<<2048, 128, 0, stream>>>(Qb, Kb, Vt, Ob);
  gemm_bt<0><<<dim3(8, 64), 256, 0, stream>>>(Ob, wo, 8192, 1024, 1024,
                                              nullptr, nullptr, nullptr, out, bout);
}

// Round 5
// 307.442 us; speedup vs baseline: 1.5712x; 1.5712x over previous
//
#include <hip/hip_runtime.h>

typedef unsigned short ushortT;
typedef __attribute__((ext_vector_type(8))) short short8;
typedef __attribute__((ext_vector_type(4))) float f32x4;

#define QSCALE 0.18033688011112042f  // (1/sqrt(64)) * log2(e)

__device__ __forceinline__ ushortT f2bf(float f) {
  union { float f; unsigned int u; } v; v.f = f;
  unsigned int r = v.u + 0x7FFFu + ((v.u >> 16) & 1u);
  return (ushortT)(r >> 16);
}

// pack two f32 -> bf16x2 (round-half-up), low16 = a, high16 = b
__device__ __forceinline__ unsigned int pk2bf(float a, float b) {
  union { float f; unsigned int u; } ua, ub; ua.f = a; ub.f = b;
  return __builtin_amdgcn_perm(ub.u + 0x8000u, ua.u + 0x8000u, 0x07060302u);
}

// gfx950 cross-quadrow swap pair: after both swaps,
// a = [A0,A2,B0,B2], b = [A1,A3,B1,B3] (16-lane chunks)
__device__ __forceinline__ void pl_swap(unsigned int& a, unsigned int& b) {
  asm("v_permlane32_swap_b32 %0, %1" : "+v"(a), "+v"(b));
  asm("v_permlane16_swap_b32 %0, %1" : "+v"(a), "+v"(b));
}

__device__ __forceinline__ void gld_lds16(const void* g, void* l) {
  __builtin_amdgcn_global_load_lds(
      (const __attribute__((address_space(1))) unsigned int*)g,
      (__attribute__((address_space(3))) unsigned int*)l, 16, 0, 0);
}

// ---------------- fp32 -> bf16 convert ----------------
__global__ __launch_bounds__(256) void cvt_kernel(const float* __restrict__ src,
                                                  ushortT* __restrict__ dst, int n4) {
  int i = blockIdx.x * 256 + threadIdx.x;
  if (i < n4) {
    float4 v = ((const float4*)src)[i];
    ushort4 o;
    o.x = f2bf(v.x); o.y = f2bf(v.y); o.z = f2bf(v.z); o.w = f2bf(v.w);
    ((ushort4*)dst)[i] = o;
  }
}

// ---------------- LayerNorm: fp32 in, bf16 out ----------------
__global__ __launch_bounds__(256) void ln_kernel(const float* __restrict__ x,
                                                 const float* __restrict__ g,
                                                 const float* __restrict__ be,
                                                 ushortT* __restrict__ xn) {
  const int row = blockIdx.x, tid = threadIdx.x;
  const float4 v = ((const float4*)(x + (size_t)row * 1024))[tid];
  float s1 = v.x + v.y + v.z + v.w;
  float s2 = v.x * v.x + v.y * v.y + v.z * v.z + v.w * v.w;
#pragma unroll
  for (int off = 32; off >= 1; off >>= 1) {
    s1 += __shfl_xor(s1, off, 64);
    s2 += __shfl_xor(s2, off, 64);
  }
  __shared__ float red[8];
  const int wave = tid >> 6, lane = tid & 63;
  if (lane == 0) { red[wave] = s1; red[4 + wave] = s2; }
  __syncthreads();
  s1 = red[0] + red[1] + red[2] + red[3];
  s2 = red[4] + red[5] + red[6] + red[7];
  const float mean = s1 * (1.0f / 1024.0f);
  const float var  = s2 * (1.0f / 1024.0f) - mean * mean;
  const float rs = rsqrtf(var + 1e-5f);
  const float4 gv = ((const float4*)g)[tid];
  const float4 bv = ((const float4*)be)[tid];
  ushort4 o;
  o.x = f2bf((v.x - mean) * rs * gv.x + bv.x);
  o.y = f2bf((v.y - mean) * rs * gv.y + bv.y);
  o.z = f2bf((v.z - mean) * rs * gv.z + bv.z);
  o.w = f2bf((v.w - mean) * rs * gv.w + bv.w);
  ((ushort4*)xn)[(size_t)row * 256 + tid] = o;
}

// ---------------- GEMM C[M,N] = A[M,K] * B[N,K]^T (both bf16, K-major) ----
// MODE 0: fp32 out + bias (final projection).  MODE 1: QKV scatter epilogue.
template <int MODE>
__global__ __launch_bounds__(256, 2) void gemm_bt(
    const ushortT* __restrict__ A, const ushortT* __restrict__ Bm,
    int M, int N, int K,
    ushortT* __restrict__ qbuf, ushortT* __restrict__ kbuf, ushortT* __restrict__ vbuf,
    float* __restrict__ outf, const float* __restrict__ bias) {
  __shared__ ushortT lds_a[128 * 64];
  __shared__ ushortT lds_b[128 * 64];
  const int tid = threadIdx.x;
  const int wave = tid >> 6, lane = tid & 63;
  const int q4 = lane >> 4, l16 = lane & 15;
  const int m0 = blockIdx.y * 128, n0 = blockIdx.x * 128;
  const int wm = (wave >> 1) * 64, wn = (wave & 1) * 64;
  const int srow = lane >> 3, scol = (lane & 7) * 8;  // staging: 8 rows x 64 cols / inst

  f32x4 acc[4][4];
#pragma unroll
  for (int i = 0; i < 4; i++)
#pragma unroll
    for (int j = 0; j < 4; j++) acc[i][j] = (f32x4){0.f, 0.f, 0.f, 0.f};

  for (int k0 = 0; k0 < K; k0 += 64) {
#pragma unroll
    for (int j = 0; j < 4; j++) {
      const int q = wave * 4 + j;  // chunk 0..15, 8 rows each
      gld_lds16(&A[(size_t)(m0 + q * 8 + srow) * K + (k0 + scol)], &lds_a[q * 512]);
      gld_lds16(&Bm[(size_t)(n0 + q * 8 + srow) * K + (k0 + scol)], &lds_b[q * 512]);
    }
    __syncthreads();  // drains vmcnt -> staged data visible
#pragma unroll
    for (int kk = 0; kk < 2; kk++) {
      short8 af[4], bf[4];
#pragma unroll
      for (int i = 0; i < 4; i++)
        af[i] = *(const short8*)&lds_a[(wm + i * 16 + l16) * 64 + kk * 32 + q4 * 8];
#pragma unroll
      for (int i = 0; i < 4; i++)
        bf[i] = *(const short8*)&lds_b[(wn + i * 16 + l16) * 64 + kk * 32 + q4 * 8];
#pragma unroll
      for (int im = 0; im < 4; im++)
#pragma unroll
        for (int in = 0; in < 4; in++)
          acc[im][in] = __builtin_amdgcn_mfma_f32_16x16x32_bf16(af[im], bf[in], acc[im][in], 0, 0, 0);
    }
    __syncthreads();  // all waves done reading before next stage overwrites
  }

  // Epilogue. C/D layout: col = lane&15, row = (lane>>4)*4 + reg.
#pragma unroll
  for (int im = 0; im < 4; im++) {
    const int grow_base = m0 + wm + im * 16 + q4 * 4;
#pragma unroll
    for (int in = 0; in < 4; in++) {
      const int c = n0 + wn + in * 16 + l16;
#pragma unroll
      for (int r = 0; r < 4; r++) {
        const float v = acc[im][in][r];
        const int grow = grow_base + r;
        if (MODE == 0) {
          outf[(size_t)grow * N + c] = v + bias[c];
        } else {
          const int which = c >> 10;          // 0=q 1=k 2=v (uniform per 16-tile)
          const int h = (c >> 6) & 15;
          const int d = c & 63;
          const int b = grow >> 11, n = grow & 2047;
          if (which == 0) {
            qbuf[((size_t)(b * 16 + h) * 2048 + n) * 64 + d] = f2bf(v * QSCALE);
          } else if (which == 1) {
            kbuf[((size_t)(b * 16 + h) * 2048 + n) * 64 + d] = f2bf(v);
          } else {  // V stored transposed: [B,H,dh,N]
            vbuf[((size_t)(b * 16 + h) * 64 + d) * 2048 + n] = f2bf(v);
          }
        }
      }
    }
  }
}

// ---------------- Flash attention v5: LDS-shared K/V + register transpose --
// Q [B,H,N,64] (pre-scaled into log2 domain), K [B,H,N,64], Vt [B,H,64,N].
// Max-free softmax (log2-domain scores O(10) << 127): P=exp2(s), l=sum.
// K/V tiles are IDENTICAL for all 4 waves of a block -> stage once per block
// via async global_load_lds, double-buffered; waves read fragments from LDS.
// P transpose stays in-register (v_permlane{32,16}_swap).
// Block = 4 waves x 32 queries = 128 queries; grid = 64 bh x 16 qt.
__global__ __launch_bounds__(256, 4) void attn_kernel(
    const ushortT* __restrict__ Qb, const ushortT* __restrict__ Kb,
    const ushortT* __restrict__ Vt, ushortT* __restrict__ Ob) {
  __shared__ ushortT kb[2][4096];  // [buf][64 keys x 64 dim], 8 KB each
  __shared__ ushortT vb[2][4096];  // [buf][64 dim x 64 keys]
  const int tid = threadIdx.x;
  const int wave = tid >> 6, lane = tid & 63;
  const int q4 = lane >> 4, l16 = lane & 15;
  const int blk = blockIdx.x;
  const int bh = blk & 63, qt = blk >> 6;  // 16 q-tiles/bh, all on one XCD
  const ushortT* Qp = Qb + (size_t)bh * (2048 * 64);
  const ushortT* Kp = Kb + (size_t)bh * (2048 * 64);
  const ushortT* Vp = Vt + (size_t)bh * (64 * 2048);
  const int qrow0 = qt * 128 + wave * 32;

  // Q fragments (B-operand: n=q=l16, k=dim=q4*8+j)
  short8 qf[2][2];
#pragma unroll
  for (int qn = 0; qn < 2; qn++)
#pragma unroll
    for (int kk = 0; kk < 2; kk++)
      qf[qn][kk] = *(const short8*)&Qp[(size_t)(qrow0 + qn * 16 + l16) * 64 + kk * 32 + q4 * 8];

  f32x4 acc[4][2];  // O^T accum [dn][qn], C-layout: d=dn*16+q4*4+r, q=l16
#pragma unroll
  for (int dn = 0; dn < 4; dn++)
#pragma unroll
    for (int qn = 0; qn < 2; qn++) acc[dn][qn] = (f32x4){0.f, 0.f, 0.f, 0.f};
  float lsum[2] = {0.f, 0.f};

  // ---- async stage of one 64-key tile (K: contiguous 8KB; V: 64 rows x 128B)
  const int vrow = tid >> 3, vcol = (tid & 7) * 8;  // V staging coords
  auto stage = [&](int buf, int s0) {
    gld_lds16(&Kp[(size_t)s0 * 64 + wave * 512 + lane * 8], &kb[buf][wave * 512]);
    gld_lds16(&Kp[(size_t)s0 * 64 + 2048 + wave * 512 + lane * 8], &kb[buf][2048 + wave * 512]);
    gld_lds16(&Vp[(size_t)vrow * 2048 + s0 + vcol], &vb[buf][wave * 512]);
    gld_lds16(&Vp[(size_t)(vrow + 32) * 2048 + s0 + vcol], &vb[buf][2048 + wave * 512]);
  };

  stage(0, 0);

  for (int t = 0; t < 32; t++) {
    const int cur = t & 1;
    __syncthreads();           // staged data for tile t visible; prev reads done
    if (t < 31) stage(cur ^ 1, (t + 1) * 64);  // async prefetch next tile

    // ---- S^T = K·Q^T : sa[qn][cn][r] = S^T[key=cn*16+q4*4+r][q=qn*16+l16]
    f32x4 sa[2][4];
#pragma unroll
    for (int qn = 0; qn < 2; qn++)
#pragma unroll
      for (int cn = 0; cn < 4; cn++) sa[qn][cn] = (f32x4){0.f, 0.f, 0.f, 0.f};
#pragma unroll
    for (int cn = 0; cn < 4; cn++) {
      const short8 kf0 = *(const short8*)&kb[cur][(cn * 16 + l16) * 64 + q4 * 8];
      const short8 kf1 = *(const short8*)&kb[cur][(cn * 16 + l16) * 64 + 32 + q4 * 8];
#pragma unroll
      for (int qn = 0; qn < 2; qn++) {
        sa[qn][cn] = __builtin_amdgcn_mfma_f32_16x16x32_bf16(kf0, qf[qn][0], sa[qn][cn], 0, 0, 0);
        sa[qn][cn] = __builtin_amdgcn_mfma_f32_16x16x32_bf16(kf1, qf[qn][1], sa[qn][cn], 0, 0, 0);
      }
    }

    // ---- max-free softmax: P = exp2(s); per-lane denominator; pack pairs
    unsigned int w[2][4][2];
#pragma unroll
    for (int qn = 0; qn < 2; qn++)
#pragma unroll
      for (int cn = 0; cn < 4; cn++) {
        float p0 = __builtin_amdgcn_exp2f(sa[qn][cn][0]);
        float p1 = __builtin_amdgcn_exp2f(sa[qn][cn][1]);
        float p2 = __builtin_amdgcn_exp2f(sa[qn][cn][2]);
        float p3 = __builtin_amdgcn_exp2f(sa[qn][cn][3]);
        lsum[qn] += (p0 + p1) + (p2 + p3);
        w[qn][cn][0] = pk2bf(p0, p1);
        w[qn][cn][1] = pk2bf(p2, p3);
      }

    // ---- in-register transpose: C-layout pairs -> B-operand fragments
    short8 pf[2][2];
#pragma unroll
    for (int qn = 0; qn < 2; qn++)
#pragma unroll
      for (int ks = 0; ks < 2; ks++) {
        unsigned int a0 = w[qn][2 * ks][0], b0 = w[qn][2 * ks + 1][0];
        unsigned int a1 = w[qn][2 * ks][1], b1 = w[qn][2 * ks + 1][1];
        pl_swap(a0, b0);
        pl_swap(a1, b1);
        union { unsigned int u[4]; short8 s; } tr;
        tr.u[0] = a0; tr.u[1] = a1; tr.u[2] = b0; tr.u[3] = b1;
        pf[qn][ks] = tr.s;
      }

    // ---- O^T += V^T·P^T
#pragma unroll
    for (int dn = 0; dn < 4; dn++) {
      const short8 vf0 = *(const short8*)&vb[cur][(dn * 16 + l16) * 64 + q4 * 8];
      const short8 vf1 = *(const short8*)&vb[cur][(dn * 16 + l16) * 64 + 32 + q4 * 8];
#pragma unroll
      for (int qn = 0; qn < 2; qn++) {
        acc[dn][qn] = __builtin_amdgcn_mfma_f32_16x16x32_bf16(vf0, pf[qn][0], acc[dn][qn], 0, 0, 0);
        acc[dn][qn] = __builtin_amdgcn_mfma_f32_16x16x32_bf16(vf1, pf[qn][1], acc[dn][qn], 0, 0, 0);
      }
    }
  }

  // ---- epilogue: reduce denominator across the 4 q4 groups, write O^T
  const int b = bh >> 4, h = bh & 15;
#pragma unroll
  for (int qn = 0; qn < 2; qn++) {
    float l = lsum[qn];
    l += __shfl_xor(l, 16, 64);
    l += __shfl_xor(l, 32, 64);
    const float inv = 1.0f / l;
    const size_t row = (size_t)(b * 2048 + qrow0 + qn * 16 + l16) * 1024 + h * 64;
#pragma unroll
    for (int dn = 0; dn < 4; dn++) {
      ushort4 o;
      o.x = f2bf(acc[dn][qn][0] * inv);
      o.y = f2bf(acc[dn][qn][1] * inv);
      o.z = f2bf(acc[dn][qn][2] * inv);
      o.w = f2bf(acc[dn][qn][3] * inv);
      *(ushort4*)&Ob[row + dn * 16 + q4 * 4] = o;
    }
  }
}

extern "C" void kernel_launch(void* const* d_in, const int* in_sizes, int n_in,
                              void* d_out, int out_size, void* d_ws, size_t ws_size,
                              hipStream_t stream) {
  const float* x    = (const float*)d_in[0];
  const float* g    = (const float*)d_in[1];
  const float* be   = (const float*)d_in[2];
  const float* wqkv = (const float*)d_in[3];
  const float* wout = (const float*)d_in[4];
  const float* bout = (const float*)d_in[5];
  float* out = (float*)d_out;

  char* ws = (char*)d_ws;
  ushortT* xn = (ushortT*)(ws + 0);                    // 16 MB  [8192,1024] bf16
  ushortT* wq = (ushortT*)(ws + 16777216);             //  6 MB  [3072,1024] bf16
  ushortT* wo = (ushortT*)(ws + 23068672);             //  2 MB  [1024,1024] bf16
  ushortT* Qb = (ushortT*)(ws + 25165824);             // 16 MB  [B,H,N,64]
  ushortT* Kb = (ushortT*)(ws + 41943040);             // 16 MB  [B,H,N,64]
  ushortT* Vt = (ushortT*)(ws + 58720256);             // 16 MB  [B,H,64,N]
  ushortT* Ob = (ushortT*)(ws + 75497472);             // 16 MB  [8192,1024]

  cvt_kernel<<<3072, 256, 0, stream>>>(wqkv, wq, 786432);
  cvt_kernel<<<1024, 256, 0, stream>>>(wout, wo, 262144);
  ln_kernel<<<8192, 256, 0, stream>>>(x, g, be, xn);
  gemm_bt<1><<<dim3(24, 64), 256, 0, stream>>>(xn, wq, 8192, 3072, 1024,
                                               Qb, Kb, Vt, nullptr, nullptr);
  attn_kernel<<<1024, 256, 0, stream>>>(Qb, Kb, Vt, Ob);
  gemm_bt<0><<<dim3(8, 64), 256, 0, stream>>>(Ob, wo, 8192, 1024, 1024,
                                              nullptr, nullptr, nullptr, out, bout);
}

// Round 6
// 300.324 us; speedup vs baseline: 1.6084x; 1.0237x over previous
//
#include <hip/hip_runtime.h>

typedef unsigned short ushortT;
typedef __attribute__((ext_vector_type(8))) short short8;
typedef __attribute__((ext_vector_type(4))) float f32x4;

#define QSCALE 0.18033688011112042f  // (1/sqrt(64)) * log2(e)

__device__ __forceinline__ ushortT f2bf(float f) {
  union { float f; unsigned int u; } v; v.f = f;
  unsigned int r = v.u + 0x7FFFu + ((v.u >> 16) & 1u);
  return (ushortT)(r >> 16);
}

// pack two f32 -> bf16x2 (round-half-up), low16 = a, high16 = b
__device__ __forceinline__ unsigned int pk2bf(float a, float b) {
  union { float f; unsigned int u; } ua, ub; ua.f = a; ub.f = b;
  return __builtin_amdgcn_perm(ub.u + 0x8000u, ua.u + 0x8000u, 0x07060302u);
}

// gfx950 cross-quadrow swap pair: after both swaps,
// a = [A0,A2,B0,B2], b = [A1,A3,B1,B3] (16-lane chunks)
__device__ __forceinline__ void pl_swap(unsigned int& a, unsigned int& b) {
  asm("v_permlane32_swap_b32 %0, %1" : "+v"(a), "+v"(b));
  asm("v_permlane16_swap_b32 %0, %1" : "+v"(a), "+v"(b));
}

__device__ __forceinline__ void gld_lds16(const void* g, void* l) {
  __builtin_amdgcn_global_load_lds(
      (const __attribute__((address_space(1))) unsigned int*)g,
      (__attribute__((address_space(3))) unsigned int*)l, 16, 0, 0);
}

// ---------------- fp32 -> bf16 convert ----------------
__global__ __launch_bounds__(256) void cvt_kernel(const float* __restrict__ src,
                                                  ushortT* __restrict__ dst, int n4) {
  int i = blockIdx.x * 256 + threadIdx.x;
  if (i < n4) {
    float4 v = ((const float4*)src)[i];
    ushort4 o;
    o.x = f2bf(v.x); o.y = f2bf(v.y); o.z = f2bf(v.z); o.w = f2bf(v.w);
    ((ushort4*)dst)[i] = o;
  }
}

// ---------------- LayerNorm: fp32 in, bf16 out ----------------
__global__ __launch_bounds__(256) void ln_kernel(const float* __restrict__ x,
                                                 const float* __restrict__ g,
                                                 const float* __restrict__ be,
                                                 ushortT* __restrict__ xn) {
  const int row = blockIdx.x, tid = threadIdx.x;
  const float4 v = ((const float4*)(x + (size_t)row * 1024))[tid];
  float s1 = v.x + v.y + v.z + v.w;
  float s2 = v.x * v.x + v.y * v.y + v.z * v.z + v.w * v.w;
#pragma unroll
  for (int off = 32; off >= 1; off >>= 1) {
    s1 += __shfl_xor(s1, off, 64);
    s2 += __shfl_xor(s2, off, 64);
  }
  __shared__ float red[8];
  const int wave = tid >> 6, lane = tid & 63;
  if (lane == 0) { red[wave] = s1; red[4 + wave] = s2; }
  __syncthreads();
  s1 = red[0] + red[1] + red[2] + red[3];
  s2 = red[4] + red[5] + red[6] + red[7];
  const float mean = s1 * (1.0f / 1024.0f);
  const float var  = s2 * (1.0f / 1024.0f) - mean * mean;
  const float rs = rsqrtf(var + 1e-5f);
  const float4 gv = ((const float4*)g)[tid];
  const float4 bv = ((const float4*)be)[tid];
  ushort4 o;
  o.x = f2bf((v.x - mean) * rs * gv.x + bv.x);
  o.y = f2bf((v.y - mean) * rs * gv.y + bv.y);
  o.z = f2bf((v.z - mean) * rs * gv.z + bv.z);
  o.w = f2bf((v.w - mean) * rs * gv.w + bv.w);
  ((ushort4*)xn)[(size_t)row * 256 + tid] = o;
}

// ---------------- GEMM C[M,N] = A[M,K] * B[N,K]^T (both bf16, K-major) ----
// LDS layout XOR-swizzled (chunk ^= row&7) -> conflict-free ds_read_b128.
// MODE 0: fp32 out + bias (final projection).  MODE 1: QKV scatter epilogue.
template <int MODE>
__global__ __launch_bounds__(256, 2) void gemm_bt(
    const ushortT* __restrict__ A, const ushortT* __restrict__ Bm,
    int M, int N, int K,
    ushortT* __restrict__ qbuf, ushortT* __restrict__ kbuf, ushortT* __restrict__ vbuf,
    float* __restrict__ outf, const float* __restrict__ bias) {
  __shared__ ushortT lds_a[128 * 64];
  __shared__ ushortT lds_b[128 * 64];
  const int tid = threadIdx.x;
  const int wave = tid >> 6, lane = tid & 63;
  const int q4 = lane >> 4, l16 = lane & 15;
  const int m0 = blockIdx.y * 128, n0 = blockIdx.x * 128;
  const int wm = (wave >> 1) * 64, wn = (wave & 1) * 64;
  const int srow = lane >> 3;                       // 8 rows x 64 cols / inst
  const int scol = ((lane & 7) ^ srow) * 8;         // XOR-swizzled source chunk
  const int sw = l16 & 7;                           // read-side swizzle factor

  f32x4 acc[4][4];
#pragma unroll
  for (int i = 0; i < 4; i++)
#pragma unroll
    for (int j = 0; j < 4; j++) acc[i][j] = (f32x4){0.f, 0.f, 0.f, 0.f};

  for (int k0 = 0; k0 < K; k0 += 64) {
#pragma unroll
    for (int j = 0; j < 4; j++) {
      const int q = wave * 4 + j;  // chunk 0..15, 8 rows each
      gld_lds16(&A[(size_t)(m0 + q * 8 + srow) * K + (k0 + scol)], &lds_a[q * 512]);
      gld_lds16(&Bm[(size_t)(n0 + q * 8 + srow) * K + (k0 + scol)], &lds_b[q * 512]);
    }
    __syncthreads();  // drains vmcnt -> staged data visible
#pragma unroll
    for (int kk = 0; kk < 2; kk++) {
      short8 af[4], bf[4];
#pragma unroll
      for (int i = 0; i < 4; i++)
        af[i] = *(const short8*)&lds_a[(wm + i * 16 + l16) * 64 + ((kk * 4 + q4) ^ sw) * 8];
#pragma unroll
      for (int i = 0; i < 4; i++)
        bf[i] = *(const short8*)&lds_b[(wn + i * 16 + l16) * 64 + ((kk * 4 + q4) ^ sw) * 8];
#pragma unroll
      for (int im = 0; im < 4; im++)
#pragma unroll
        for (int in = 0; in < 4; in++)
          acc[im][in] = __builtin_amdgcn_mfma_f32_16x16x32_bf16(af[im], bf[in], acc[im][in], 0, 0, 0);
    }
    __syncthreads();  // all waves done reading before next stage overwrites
  }

  // Epilogue. C/D layout: col = lane&15, row = (lane>>4)*4 + reg.
#pragma unroll
  for (int im = 0; im < 4; im++) {
    const int grow_base = m0 + wm + im * 16 + q4 * 4;
#pragma unroll
    for (int in = 0; in < 4; in++) {
      const int c = n0 + wn + in * 16 + l16;
#pragma unroll
      for (int r = 0; r < 4; r++) {
        const float v = acc[im][in][r];
        const int grow = grow_base + r;
        if (MODE == 0) {
          outf[(size_t)grow * N + c] = v + bias[c];
        } else {
          const int which = c >> 10;          // 0=q 1=k 2=v (uniform per 16-tile)
          const int h = (c >> 6) & 15;
          const int d = c & 63;
          const int b = grow >> 11, n = grow & 2047;
          if (which == 0) {
            qbuf[((size_t)(b * 16 + h) * 2048 + n) * 64 + d] = f2bf(v * QSCALE);
          } else if (which == 1) {
            kbuf[((size_t)(b * 16 + h) * 2048 + n) * 64 + d] = f2bf(v);
          } else {  // V stored transposed: [B,H,dh,N]
            vbuf[((size_t)(b * 16 + h) * 64 + d) * 2048 + n] = f2bf(v);
          }
        }
      }
    }
  }
}

// ---------------- Flash attention v6: swizzled LDS K/V, 64 q/wave ----------
// Q [B,H,N,64] (pre-scaled into log2 domain), K [B,H,N,64], Vt [B,H,64,N].
// Max-free softmax (log2-domain scores O(10) << 127): P=exp2(s), l=sum.
// K/V staged once per block (async global_load_lds, double-buffered) with
// XOR-swizzled chunks -> conflict-free ds_read_b128. 64 queries per wave
// halves per-CU LDS read traffic vs 32. In-register P transpose (permlane).
// Block = 4 waves x 64 q = 256 q; grid = 64 bh x 8 qt = 512 (2 blocks/CU).
__global__ __launch_bounds__(256, 2) void attn_kernel(
    const ushortT* __restrict__ Qb, const ushortT* __restrict__ Kb,
    const ushortT* __restrict__ Vt, ushortT* __restrict__ Ob) {
  __shared__ ushortT kb[2][4096];  // [buf][64 keys x 64 dim], 8 KB each
  __shared__ ushortT vb[2][4096];  // [buf][64 dim x 64 keys]
  const int tid = threadIdx.x;
  const int wave = tid >> 6, lane = tid & 63;
  const int q4 = lane >> 4, l16 = lane & 15;
  const int sw = l16 & 7;  // read-side swizzle factor
  const int blk = blockIdx.x;
  const int bh = blk & 63, qt = blk >> 6;  // 8 q-tiles/bh, all on one XCD
  const ushortT* Qp = Qb + (size_t)bh * (2048 * 64);
  const ushortT* Kp = Kb + (size_t)bh * (2048 * 64);
  const ushortT* Vp = Vt + (size_t)bh * (64 * 2048);
  const int qrow0 = qt * 256 + wave * 64;

  // Q fragments (B-operand: n=q=l16, k=dim=q4*8+j), qn in {0..3}
  short8 qf[4][2];
#pragma unroll
  for (int qn = 0; qn < 4; qn++)
#pragma unroll
    for (int kk = 0; kk < 2; kk++)
      qf[qn][kk] = *(const short8*)&Qp[(size_t)(qrow0 + qn * 16 + l16) * 64 + kk * 32 + q4 * 8];

  f32x4 acc[4][4];  // O^T accum [dn][qn], C-layout: d=dn*16+q4*4+r, q=l16
#pragma unroll
  for (int dn = 0; dn < 4; dn++)
#pragma unroll
    for (int qn = 0; qn < 4; qn++) acc[dn][qn] = (f32x4){0.f, 0.f, 0.f, 0.f};
  float lsum[4] = {0.f, 0.f, 0.f, 0.f};

  // ---- async stage of one 64-key tile, XOR-swizzled source chunks
  const int krow = lane >> 3, kchk = ((lane & 7) ^ (lane >> 3)) * 8;
  const int vrow = tid >> 3, vchk = ((tid & 7) ^ ((tid >> 3) & 7)) * 8;
  auto stage = [&](int buf, int s0) {
    gld_lds16(&Kp[(size_t)(s0 + wave * 8 + krow) * 64 + kchk], &kb[buf][wave * 512]);
    gld_lds16(&Kp[(size_t)(s0 + 32 + wave * 8 + krow) * 64 + kchk], &kb[buf][2048 + wave * 512]);
    gld_lds16(&Vp[(size_t)vrow * 2048 + s0 + vchk], &vb[buf][wave * 512]);
    gld_lds16(&Vp[(size_t)(vrow + 32) * 2048 + s0 + vchk], &vb[buf][2048 + wave * 512]);
  };

  stage(0, 0);

  for (int t = 0; t < 32; t++) {
    const int cur = t & 1;
    __syncthreads();           // staged data for tile t visible; prev reads done
    if (t < 31) stage(cur ^ 1, (t + 1) * 64);  // async prefetch next tile

    // ---- S^T = K·Q^T : sa[qn][cn][r] = S^T[key=cn*16+q4*4+r][q=qn*16+l16]
    f32x4 sa[4][4];
#pragma unroll
    for (int qn = 0; qn < 4; qn++)
#pragma unroll
      for (int cn = 0; cn < 4; cn++) sa[qn][cn] = (f32x4){0.f, 0.f, 0.f, 0.f};
#pragma unroll
    for (int cn = 0; cn < 4; cn++) {
      const short8 kf0 = *(const short8*)&kb[cur][(cn * 16 + l16) * 64 + (q4 ^ sw) * 8];
      const short8 kf1 = *(const short8*)&kb[cur][(cn * 16 + l16) * 64 + ((q4 + 4) ^ sw) * 8];
#pragma unroll
      for (int qn = 0; qn < 4; qn++) {
        sa[qn][cn] = __builtin_amdgcn_mfma_f32_16x16x32_bf16(kf0, qf[qn][0], sa[qn][cn], 0, 0, 0);
        sa[qn][cn] = __builtin_amdgcn_mfma_f32_16x16x32_bf16(kf1, qf[qn][1], sa[qn][cn], 0, 0, 0);
      }
    }

    // ---- max-free softmax + in-register transpose, then PV
    short8 pf[4][2];
#pragma unroll
    for (int qn = 0; qn < 4; qn++) {
      unsigned int w[4][2];
#pragma unroll
      for (int cn = 0; cn < 4; cn++) {
        float p0 = __builtin_amdgcn_exp2f(sa[qn][cn][0]);
        float p1 = __builtin_amdgcn_exp2f(sa[qn][cn][1]);
        float p2 = __builtin_amdgcn_exp2f(sa[qn][cn][2]);
        float p3 = __builtin_amdgcn_exp2f(sa[qn][cn][3]);
        lsum[qn] += (p0 + p1) + (p2 + p3);
        w[cn][0] = pk2bf(p0, p1);
        w[cn][1] = pk2bf(p2, p3);
      }
#pragma unroll
      for (int ks = 0; ks < 2; ks++) {
        unsigned int a0 = w[2 * ks][0], b0 = w[2 * ks + 1][0];
        unsigned int a1 = w[2 * ks][1], b1 = w[2 * ks + 1][1];
        pl_swap(a0, b0);
        pl_swap(a1, b1);
        union { unsigned int u[4]; short8 s; } tr;
        tr.u[0] = a0; tr.u[1] = a1; tr.u[2] = b0; tr.u[3] = b1;
        pf[qn][ks] = tr.s;
      }
    }

    // ---- O^T += V^T·P^T
#pragma unroll
    for (int dn = 0; dn < 4; dn++) {
      const short8 vf0 = *(const short8*)&vb[cur][(dn * 16 + l16) * 64 + (q4 ^ sw) * 8];
      const short8 vf1 = *(const short8*)&vb[cur][(dn * 16 + l16) * 64 + ((q4 + 4) ^ sw) * 8];
#pragma unroll
      for (int qn = 0; qn < 4; qn++) {
        acc[dn][qn] = __builtin_amdgcn_mfma_f32_16x16x32_bf16(vf0, pf[qn][0], acc[dn][qn], 0, 0, 0);
        acc[dn][qn] = __builtin_amdgcn_mfma_f32_16x16x32_bf16(vf1, pf[qn][1], acc[dn][qn], 0, 0, 0);
      }
    }
  }

  // ---- epilogue: reduce denominator across the 4 q4 groups, write O^T
  const int b = bh >> 4, h = bh & 15;
#pragma unroll
  for (int qn = 0; qn < 4; qn++) {
    float l = lsum[qn];
    l += __shfl_xor(l, 16, 64);
    l += __shfl_xor(l, 32, 64);
    const float inv = 1.0f / l;
    const size_t row = (size_t)(b * 2048 + qrow0 + qn * 16 + l16) * 1024 + h * 64;
#pragma unroll
    for (int dn = 0; dn < 4; dn++) {
      ushort4 o;
      o.x = f2bf(acc[dn][qn][0] * inv);
      o.y = f2bf(acc[dn][qn][1] * inv);
      o.z = f2bf(acc[dn][qn][2] * inv);
      o.w = f2bf(acc[dn][qn][3] * inv);
      *(ushort4*)&Ob[row + dn * 16 + q4 * 4] = o;
    }
  }
}

extern "C" void kernel_launch(void* const* d_in, const int* in_sizes, int n_in,
                              void* d_out, int out_size, void* d_ws, size_t ws_size,
                              hipStream_t stream) {
  const float* x    = (const float*)d_in[0];
  const float* g    = (const float*)d_in[1];
  const float* be   = (const float*)d_in[2];
  const float* wqkv = (const float*)d_in[3];
  const float* wout = (const float*)d_in[4];
  const float* bout = (const float*)d_in[5];
  float* out = (float*)d_out;

  char* ws = (char*)d_ws;
  ushortT* xn = (ushortT*)(ws + 0);                    // 16 MB  [8192,1024] bf16
  ushortT* wq = (ushortT*)(ws + 16777216);             //  6 MB  [3072,1024] bf16
  ushortT* wo = (ushortT*)(ws + 23068672);             //  2 MB  [1024,1024] bf16
  ushortT* Qb = (ushortT*)(ws + 25165824);             // 16 MB  [B,H,N,64]
  ushortT* Kb = (ushortT*)(ws + 41943040);             // 16 MB  [B,H,N,64]
  ushortT* Vt = (ushortT*)(ws + 58720256);             // 16 MB  [B,H,64,N]
  ushortT* Ob = (ushortT*)(ws + 75497472);             // 16 MB  [8192,1024]

  cvt_kernel<<<3072, 256, 0, stream>>>(wqkv, wq, 786432);
  cvt_kernel<<<1024, 256, 0, stream>>>(wout, wo, 262144);
  ln_kernel<<<8192, 256, 0, stream>>>(x, g, be, xn);
  gemm_bt<1><<<dim3(24, 64), 256, 0, stream>>>(xn, wq, 8192, 3072, 1024,
                                               Qb, Kb, Vt, nullptr, nullptr);
  attn_kernel<<<512, 256, 0, stream>>>(Qb, Kb, Vt, Ob);
  gemm_bt<0><<<dim3(8, 64), 256, 0, stream>>>(Ob, wo, 8192, 1024, 1024,
                                              nullptr, nullptr, nullptr, out, bout);
}

// Round 7
// 265.658 us; speedup vs baseline: 1.8183x; 1.1305x over previous
//
#include <hip/hip_runtime.h>

typedef unsigned short ushortT;
typedef __attribute__((ext_vector_type(8))) short short8;
typedef __attribute__((ext_vector_type(4))) float f32x4;

#define QSCALE 0.18033688011112042f  // (1/sqrt(64)) * log2(e)

__device__ __forceinline__ ushortT f2bf(float f) {
  union { float f; unsigned int u; } v; v.f = f;
  unsigned int r = v.u + 0x7FFFu + ((v.u >> 16) & 1u);
  return (ushortT)(r >> 16);
}

// pack two f32 -> bf16x2 (round-half-up), low16 = a, high16 = b
__device__ __forceinline__ unsigned int pk2bf(float a, float b) {
  union { float f; unsigned int u; } ua, ub; ua.f = a; ub.f = b;
  return __builtin_amdgcn_perm(ub.u + 0x8000u, ua.u + 0x8000u, 0x07060302u);
}

// gfx950 cross-quadrow swap pair: transposes two stacked 16x16 C-tiles
// (packed bf16 pairs) into "lane holds 8 consecutive rows for its column".
__device__ __forceinline__ void pl_swap(unsigned int& a, unsigned int& b) {
  asm("v_permlane32_swap_b32 %0, %1" : "+v"(a), "+v"(b));
  asm("v_permlane16_swap_b32 %0, %1" : "+v"(a), "+v"(b));
}

__device__ __forceinline__ void gld_lds16(const void* g, void* l) {
  __builtin_amdgcn_global_load_lds(
      (const __attribute__((address_space(1))) unsigned int*)g,
      (__attribute__((address_space(3))) unsigned int*)l, 16, 0, 0);
}

// ---------------- fp32 -> bf16 convert; elems < qlimit*4 scaled -----------
__global__ __launch_bounds__(256) void cvt_kernel(const float* __restrict__ src,
                                                  ushortT* __restrict__ dst, int n4,
                                                  int qlimit4, float scale) {
  int i = blockIdx.x * 256 + threadIdx.x;
  if (i < n4) {
    float4 v = ((const float4*)src)[i];
    const float s = (i < qlimit4) ? scale : 1.0f;
    ushort4 o;
    o.x = f2bf(v.x * s); o.y = f2bf(v.y * s); o.z = f2bf(v.z * s); o.w = f2bf(v.w * s);
    ((ushort4*)dst)[i] = o;
  }
}

// ---------------- LayerNorm: fp32 in, bf16 out ----------------
__global__ __launch_bounds__(256) void ln_kernel(const float* __restrict__ x,
                                                 const float* __restrict__ g,
                                                 const float* __restrict__ be,
                                                 ushortT* __restrict__ xn) {
  const int row = blockIdx.x, tid = threadIdx.x;
  const float4 v = ((const float4*)(x + (size_t)row * 1024))[tid];
  float s1 = v.x + v.y + v.z + v.w;
  float s2 = v.x * v.x + v.y * v.y + v.z * v.z + v.w * v.w;
#pragma unroll
  for (int off = 32; off >= 1; off >>= 1) {
    s1 += __shfl_xor(s1, off, 64);
    s2 += __shfl_xor(s2, off, 64);
  }
  __shared__ float red[8];
  const int wave = tid >> 6, lane = tid & 63;
  if (lane == 0) { red[wave] = s1; red[4 + wave] = s2; }
  __syncthreads();
  s1 = red[0] + red[1] + red[2] + red[3];
  s2 = red[4] + red[5] + red[6] + red[7];
  const float mean = s1 * (1.0f / 1024.0f);
  const float var  = s2 * (1.0f / 1024.0f) - mean * mean;
  const float rs = rsqrtf(var + 1e-5f);
  const float4 gv = ((const float4*)g)[tid];
  const float4 bv = ((const float4*)be)[tid];
  ushort4 o;
  o.x = f2bf((v.x - mean) * rs * gv.x + bv.x);
  o.y = f2bf((v.y - mean) * rs * gv.y + bv.y);
  o.z = f2bf((v.z - mean) * rs * gv.z + bv.z);
  o.w = f2bf((v.w - mean) * rs * gv.w + bv.w);
  ((ushort4*)xn)[(size_t)row * 256 + tid] = o;
}

// ---------------- GEMM C[M,N] = A[M,K] * B[N,K]^T (both bf16, K-major) ----
// LDS XOR-swizzled -> conflict-free ds_read_b128.
// MODE 0: fp32 out + bias.  MODE 1: QKV epilogue — Q/K natural row-major
// into qk[8192][2048]; V in-register transposed (pl_swap) -> Vt[B,H,64,N]
// with b128 stores (64B-coalesced per Vt row).
template <int MODE>
__global__ __launch_bounds__(256, 2) void gemm_bt(
    const ushortT* __restrict__ A, const ushortT* __restrict__ Bm,
    int M, int N, int K,
    ushortT* __restrict__ qkbuf, ushortT* __restrict__ vbuf,
    float* __restrict__ outf, const float* __restrict__ bias) {
  __shared__ ushortT lds_a[128 * 64];
  __shared__ ushortT lds_b[128 * 64];
  const int tid = threadIdx.x;
  const int wave = tid >> 6, lane = tid & 63;
  const int q4 = lane >> 4, l16 = lane & 15;
  const int m0 = blockIdx.y * 128, n0 = blockIdx.x * 128;
  const int wm = (wave >> 1) * 64, wn = (wave & 1) * 64;
  const int srow = lane >> 3;                       // 8 rows x 64 cols / inst
  const int scol = ((lane & 7) ^ srow) * 8;         // XOR-swizzled source chunk
  const int sw = l16 & 7;                           // read-side swizzle factor

  f32x4 acc[4][4];
#pragma unroll
  for (int i = 0; i < 4; i++)
#pragma unroll
    for (int j = 0; j < 4; j++) acc[i][j] = (f32x4){0.f, 0.f, 0.f, 0.f};

  for (int k0 = 0; k0 < K; k0 += 64) {
#pragma unroll
    for (int j = 0; j < 4; j++) {
      const int q = wave * 4 + j;  // chunk 0..15, 8 rows each
      gld_lds16(&A[(size_t)(m0 + q * 8 + srow) * K + (k0 + scol)], &lds_a[q * 512]);
      gld_lds16(&Bm[(size_t)(n0 + q * 8 + srow) * K + (k0 + scol)], &lds_b[q * 512]);
    }
    __syncthreads();  // drains vmcnt -> staged data visible
#pragma unroll
    for (int kk = 0; kk < 2; kk++) {
      short8 af[4], bf[4];
#pragma unroll
      for (int i = 0; i < 4; i++)
        af[i] = *(const short8*)&lds_a[(wm + i * 16 + l16) * 64 + ((kk * 4 + q4) ^ sw) * 8];
#pragma unroll
      for (int i = 0; i < 4; i++)
        bf[i] = *(const short8*)&lds_b[(wn + i * 16 + l16) * 64 + ((kk * 4 + q4) ^ sw) * 8];
#pragma unroll
      for (int im = 0; im < 4; im++)
#pragma unroll
        for (int in = 0; in < 4; in++)
          acc[im][in] = __builtin_amdgcn_mfma_f32_16x16x32_bf16(af[im], bf[in], acc[im][in], 0, 0, 0);
    }
    __syncthreads();  // all waves done reading before next stage overwrites
  }

  // Epilogue. C/D layout: col = lane&15, row = (lane>>4)*4 + reg.
  if (MODE == 0) {
#pragma unroll
    for (int im = 0; im < 4; im++)
#pragma unroll
      for (int in = 0; in < 4; in++) {
        const int c = n0 + wn + in * 16 + l16;
#pragma unroll
        for (int r = 0; r < 4; r++)
          outf[(size_t)(m0 + wm + im * 16 + q4 * 4 + r) * N + c] = acc[im][in][r] + bias[c];
      }
  } else if (n0 < 2048) {
    // Q/K: natural row-major bf16 into qk[8192][2048]
#pragma unroll
    for (int im = 0; im < 4; im++)
#pragma unroll
      for (int in = 0; in < 4; in++) {
        const int c = n0 + wn + in * 16 + l16;
#pragma unroll
        for (int r = 0; r < 4; r++)
          qkbuf[(size_t)(m0 + wm + im * 16 + q4 * 4 + r) * 2048 + c] = f2bf(acc[im][in][r]);
      }
  } else {
    // V: transpose two stacked 16x16 tiles in-register -> Vt[B,H,64,N]
#pragma unroll
    for (int j = 0; j < 2; j++) {
      const int t0 = m0 + wm + j * 32 + q4 * 8;   // 8 consecutive tokens / lane
      const int b = t0 >> 11, n = t0 & 2047;
#pragma unroll
      for (int in = 0; in < 4; in++) {
        const int cg = n0 - 2048 + wn + in * 16 + l16;  // v-channel
        const int h = cg >> 6, d = cg & 63;
        unsigned int a0 = pk2bf(acc[2 * j][in][0], acc[2 * j][in][1]);
        unsigned int a1 = pk2bf(acc[2 * j][in][2], acc[2 * j][in][3]);
        unsigned int b0 = pk2bf(acc[2 * j + 1][in][0], acc[2 * j + 1][in][1]);
        unsigned int b1 = pk2bf(acc[2 * j + 1][in][2], acc[2 * j + 1][in][3]);
        pl_swap(a0, b0);
        pl_swap(a1, b1);
        union { unsigned int u[4]; short8 s; } tr;
        tr.u[0] = a0; tr.u[1] = a1; tr.u[2] = b0; tr.u[3] = b1;
        *(short8*)&vbuf[((size_t)((b * 16 + h) * 64 + d)) * 2048 + n] = tr.s;
      }
    }
  }
}

// ---------------- Flash attention v7: Q/K from natural-layout QK buffer ----
// QK [8192][2048] bf16 (ch 0..1023 = Q pre-scaled via weights, 1024.. = K),
// Vt [B,H,64,N]. Max-free softmax; swizzled LDS K/V staging; in-register
// P transpose. Block = 4 waves x 64 q; grid = 64 bh x 8 qt (2 blocks/CU).
__global__ __launch_bounds__(256, 2) void attn_kernel(
    const ushortT* __restrict__ QK, const ushortT* __restrict__ Vt,
    ushortT* __restrict__ Ob) {
  __shared__ ushortT kb[2][4096];  // [buf][64 keys x 64 dim], 8 KB each
  __shared__ ushortT vb[2][4096];  // [buf][64 dim x 64 keys]
  const int tid = threadIdx.x;
  const int wave = tid >> 6, lane = tid & 63;
  const int q4 = lane >> 4, l16 = lane & 15;
  const int sw = l16 & 7;  // read-side swizzle factor
  const int blk = blockIdx.x;
  const int bh = blk & 63, qt = blk >> 6;  // 8 q-tiles/bh, all on one XCD
  const int b = bh >> 4, h = bh & 15;
  const ushortT* Qp = QK + (size_t)b * 2048 * 2048 + h * 64;
  const ushortT* Kp = Qp + 1024;
  const ushortT* Vp = Vt + (size_t)bh * (64 * 2048);
  const int qrow0 = qt * 256 + wave * 64;

  // Q fragments (B-operand: n=q=l16, k=dim=q4*8+j), qn in {0..3}
  short8 qf[4][2];
#pragma unroll
  for (int qn = 0; qn < 4; qn++)
#pragma unroll
    for (int kk = 0; kk < 2; kk++)
      qf[qn][kk] = *(const short8*)&Qp[(size_t)(qrow0 + qn * 16 + l16) * 2048 + kk * 32 + q4 * 8];

  f32x4 acc[4][4];  // O^T accum [dn][qn], C-layout: d=dn*16+q4*4+r, q=l16
#pragma unroll
  for (int dn = 0; dn < 4; dn++)
#pragma unroll
    for (int qn = 0; qn < 4; qn++) acc[dn][qn] = (f32x4){0.f, 0.f, 0.f, 0.f};
  float lsum[4] = {0.f, 0.f, 0.f, 0.f};

  // ---- async stage of one 64-key tile, XOR-swizzled source chunks
  const int krow = lane >> 3, kchk = ((lane & 7) ^ (lane >> 3)) * 8;
  const int vrow = tid >> 3, vchk = ((tid & 7) ^ ((tid >> 3) & 7)) * 8;
  auto stage = [&](int buf, int s0) {
    gld_lds16(&Kp[(size_t)(s0 + wave * 8 + krow) * 2048 + kchk], &kb[buf][wave * 512]);
    gld_lds16(&Kp[(size_t)(s0 + 32 + wave * 8 + krow) * 2048 + kchk], &kb[buf][2048 + wave * 512]);
    gld_lds16(&Vp[(size_t)vrow * 2048 + s0 + vchk], &vb[buf][wave * 512]);
    gld_lds16(&Vp[(size_t)(vrow + 32) * 2048 + s0 + vchk], &vb[buf][2048 + wave * 512]);
  };

  stage(0, 0);

  for (int t = 0; t < 32; t++) {
    const int cur = t & 1;
    __syncthreads();           // staged data for tile t visible; prev reads done
    if (t < 31) stage(cur ^ 1, (t + 1) * 64);  // async prefetch next tile

    // ---- S^T = K·Q^T : sa[qn][cn][r] = S^T[key=cn*16+q4*4+r][q=qn*16+l16]
    f32x4 sa[4][4];
#pragma unroll
    for (int qn = 0; qn < 4; qn++)
#pragma unroll
      for (int cn = 0; cn < 4; cn++) sa[qn][cn] = (f32x4){0.f, 0.f, 0.f, 0.f};
#pragma unroll
    for (int cn = 0; cn < 4; cn++) {
      const short8 kf0 = *(const short8*)&kb[cur][(cn * 16 + l16) * 64 + (q4 ^ sw) * 8];
      const short8 kf1 = *(const short8*)&kb[cur][(cn * 16 + l16) * 64 + ((q4 + 4) ^ sw) * 8];
#pragma unroll
      for (int qn = 0; qn < 4; qn++) {
        sa[qn][cn] = __builtin_amdgcn_mfma_f32_16x16x32_bf16(kf0, qf[qn][0], sa[qn][cn], 0, 0, 0);
        sa[qn][cn] = __builtin_amdgcn_mfma_f32_16x16x32_bf16(kf1, qf[qn][1], sa[qn][cn], 0, 0, 0);
      }
    }

    // ---- max-free softmax + in-register transpose
    short8 pf[4][2];
#pragma unroll
    for (int qn = 0; qn < 4; qn++) {
      unsigned int w[4][2];
#pragma unroll
      for (int cn = 0; cn < 4; cn++) {
        float p0 = __builtin_amdgcn_exp2f(sa[qn][cn][0]);
        float p1 = __builtin_amdgcn_exp2f(sa[qn][cn][1]);
        float p2 = __builtin_amdgcn_exp2f(sa[qn][cn][2]);
        float p3 = __builtin_amdgcn_exp2f(sa[qn][cn][3]);
        lsum[qn] += (p0 + p1) + (p2 + p3);
        w[cn][0] = pk2bf(p0, p1);
        w[cn][1] = pk2bf(p2, p3);
      }
#pragma unroll
      for (int ks = 0; ks < 2; ks++) {
        unsigned int a0 = w[2 * ks][0], b0 = w[2 * ks + 1][0];
        unsigned int a1 = w[2 * ks][1], b1 = w[2 * ks + 1][1];
        pl_swap(a0, b0);
        pl_swap(a1, b1);
        union { unsigned int u[4]; short8 s; } tr;
        tr.u[0] = a0; tr.u[1] = a1; tr.u[2] = b0; tr.u[3] = b1;
        pf[qn][ks] = tr.s;
      }
    }

    // ---- O^T += V^T·P^T
#pragma unroll
    for (int dn = 0; dn < 4; dn++) {
      const short8 vf0 = *(const short8*)&vb[cur][(dn * 16 + l16) * 64 + (q4 ^ sw) * 8];
      const short8 vf1 = *(const short8*)&vb[cur][(dn * 16 + l16) * 64 + ((q4 + 4) ^ sw) * 8];
#pragma unroll
      for (int qn = 0; qn < 4; qn++) {
        acc[dn][qn] = __builtin_amdgcn_mfma_f32_16x16x32_bf16(vf0, pf[qn][0], acc[dn][qn], 0, 0, 0);
        acc[dn][qn] = __builtin_amdgcn_mfma_f32_16x16x32_bf16(vf1, pf[qn][1], acc[dn][qn], 0, 0, 0);
      }
    }
  }

  // ---- epilogue: reduce denominator across the 4 q4 groups, write O^T
#pragma unroll
  for (int qn = 0; qn < 4; qn++) {
    float l = lsum[qn];
    l += __shfl_xor(l, 16, 64);
    l += __shfl_xor(l, 32, 64);
    const float inv = 1.0f / l;
    const size_t row = (size_t)(b * 2048 + qrow0 + qn * 16 + l16) * 1024 + h * 64;
#pragma unroll
    for (int dn = 0; dn < 4; dn++) {
      ushort4 o;
      o.x = f2bf(acc[dn][qn][0] * inv);
      o.y = f2bf(acc[dn][qn][1] * inv);
      o.z = f2bf(acc[dn][qn][2] * inv);
      o.w = f2bf(acc[dn][qn][3] * inv);
      *(ushort4*)&Ob[row + dn * 16 + q4 * 4] = o;
    }
  }
}

extern "C" void kernel_launch(void* const* d_in, const int* in_sizes, int n_in,
                              void* d_out, int out_size, void* d_ws, size_t ws_size,
                              hipStream_t stream) {
  const float* x    = (const float*)d_in[0];
  const float* g    = (const float*)d_in[1];
  const float* be   = (const float*)d_in[2];
  const float* wqkv = (const float*)d_in[3];
  const float* wout = (const float*)d_in[4];
  const float* bout = (const float*)d_in[5];
  float* out = (float*)d_out;

  char* ws = (char*)d_ws;
  ushortT* xn = (ushortT*)(ws + 0);                    // 16 MB  [8192,1024] bf16
  ushortT* wq = (ushortT*)(ws + 16777216);             //  6 MB  [3072,1024] bf16 (q rows pre-scaled)
  ushortT* wo = (ushortT*)(ws + 23068672);             //  2 MB  [1024,1024] bf16
  ushortT* QK = (ushortT*)(ws + 25165824);             // 32 MB  [8192,2048]
  ushortT* Vt = (ushortT*)(ws + 58720256);             // 16 MB  [B,H,64,N]
  ushortT* Ob = (ushortT*)(ws + 75497472);             // 16 MB  [8192,1024]

  cvt_kernel<<<3072, 256, 0, stream>>>(wqkv, wq, 786432, 262144, QSCALE);
  cvt_kernel<<<1024, 256, 0, stream>>>(wout, wo, 262144, 0, 1.0f);
  ln_kernel<<<8192, 256, 0, stream>>>(x, g, be, xn);
  gemm_bt<1><<<dim3(24, 64), 256, 0, stream>>>(xn, wq, 8192, 3072, 1024,
                                               QK, Vt, nullptr, nullptr);
  attn_kernel<<<512, 256, 0, stream>>>(QK, Vt, Ob);
  gemm_bt<0><<<dim3(8, 64), 256, 0, stream>>>(Ob, wo, 8192, 1024, 1024,
                                              nullptr, nullptr, out, bout);
}